// Round 14
// baseline (47.597 us; speedup 1.0000x reference)
//
#include <hip/hip_runtime.h>
#include <hip/hip_bf16.h>

// LinearMinimumBit: y = x @ dequant3bit(W)^T + bias
// x:[64,8192] f32, weight_q3:[4194304,6] int32 (one byte value per int32),
// weight_norm:[4194304] f32, bias:[8192] f32 -> out:[64,8192] f32
//
// Round 14: r12's PROVEN sync skeleton (2-buffer, one __syncthreads per tile,
// STAGE-then-COMPUTE) with three attributable fixes:
//  - BN=128 (A restage 134->67 MB), KS=16
//  - norms: prologue plain loads -> transposed NRM[group][row] (conflict-free
//    reads; r12's layout was a 16-way bank conflict, 6.3M cycles)
//  - steady STAGE = exactly 5 x 16B DMAs (3 pk via magic-div-96 + 2 A swizzled)
// Counted-vmcnt shelved: r13's race is attributed to spill-induced vmcnt
// miscount (scratch ops count against vmcnt); needs compile-time spill check.
//
// ws: [0,1MB) x as bf16; [1MB, 1MB+KS*2MB) partials [KS][64][8192] f32

#define BATCH   64
#define IN_F    8192
#define OUT_F   8192

#define PK_BYTES 12288   // packed weights/tile: 128 rows * 96 B (4 groups * 24 B)
#define PA_BYTES 8192    // A tile: 64 rows * 128 B (64 k * bf16), XOR-swizzled
#define BUF_BYTES (PK_BYTES + PA_BYTES)  // 20480

typedef __attribute__((ext_vector_type(8))) short bf16x8;
typedef __attribute__((ext_vector_type(4))) float f32x4;

__device__ __forceinline__ ushort f2bf(float f) {
  union { float f; unsigned u; } a; a.f = f;
  unsigned r = a.u + 0x7fffu + ((a.u >> 16) & 1u);
  return (ushort)(r >> 16);
}

__device__ __forceinline__ void gl_lds16(const void* g, void* l) {
  __builtin_amdgcn_global_load_lds((const __attribute__((address_space(1))) void*)g,
                                   (__attribute__((address_space(3))) void*)l, 16, 0, 0);
}

__global__ void __launch_bounds__(256) xcvt_kernel(const float* __restrict__ x,
                                                   ushort* __restrict__ xb) {
  int i = blockIdx.x * 256 + threadIdx.x;
  float4 v = ((const float4*)x)[i];
  ushort4 o;
  o.x = f2bf(v.x); o.y = f2bf(v.y); o.z = f2bf(v.z); o.w = f2bf(v.w);
  ((ushort4*)xb)[i] = o;
}

// 3 byte-values + norm -> 8 bf16 weights (w = v*(2n/7) - n), k-ascending
__device__ __forceinline__ bf16x8 dqfrag(int b0, int b1, int b2, float nrm) {
  float c1 = nrm * (2.0f / 7.0f);
  float c0 = nrm;
  int v0 = (b0 >> 5) & 7;
  int v1 = (b0 >> 2) & 7;
  int v2 = ((b0 & 3) << 1) | ((b1 >> 7) & 1);
  int v3 = (b1 >> 4) & 7;
  int v4 = (b1 >> 1) & 7;
  int v5 = ((b1 & 1) << 2) | ((b2 >> 6) & 3);
  int v6 = (b2 >> 3) & 7;
  int v7 = b2 & 7;
  union { __hip_bfloat162 h[4]; bf16x8 v; } r;
  r.h[0] = __float22bfloat162_rn(make_float2(fmaf((float)v0, c1, -c0), fmaf((float)v1, c1, -c0)));
  r.h[1] = __float22bfloat162_rn(make_float2(fmaf((float)v2, c1, -c0), fmaf((float)v3, c1, -c0)));
  r.h[2] = __float22bfloat162_rn(make_float2(fmaf((float)v4, c1, -c0), fmaf((float)v5, c1, -c0)));
  r.h[3] = __float22bfloat162_rn(make_float2(fmaf((float)v6, c1, -c0), fmaf((float)v7, c1, -c0)));
  return r.v;
}

template <int KS>
__global__ void __launch_bounds__(256) gemm3b_kernel(const ushort* __restrict__ xb,
                                                     const int* __restrict__ wq,
                                                     const float* __restrict__ wnorm,
                                                     float* __restrict__ partial) {
  constexpr int K_SLICE = IN_F / KS;      // 512 @KS=16
  constexpr int NTILE   = K_SLICE / 64;   // 8   @KS=16
  constexpr int NGROW   = K_SLICE / 16;   // 32  @KS=16
  constexpr int QPR     = NGROW / 4;      // float4 quads per norm row (8 @KS=16)

  __shared__ __align__(16) char  LDS[2][BUF_BYTES];   // 40 KB
  __shared__ __align__(16) float NRM[NGROW * 128];    // [group][row], 16 KB @KS=16

  const int tid  = threadIdx.x;
  const int lane = tid & 63;
  const int w    = tid >> 6;          // wave w owns cols [nb128 + w*32, +32)
  const int l15  = lane & 15;
  const int h    = lane >> 4;         // k-chunk within 32-k
  const int nb128 = blockIdx.x * 128;
  const int s    = blockIdx.y;
  const int kbase = s * K_SLICE;
  const int kg0   = kbase >> 4;       // = s * NGROW

  const char* wqp = (const char*)wq + (size_t)nb128 * 12288 + (size_t)kg0 * 24;
  const char* xbp = (const char*)xb + (size_t)kbase * 2;

  f32x4 acc[2][4];
  #pragma unroll
  for (int n = 0; n < 2; ++n)
    #pragma unroll
    for (int m = 0; m < 4; ++m) acc[n][m] = (f32x4){0.f, 0.f, 0.f, 0.f};

  // --- prologue: norms via plain loads into transposed NRM[group][row] ---
  // Visibility: loop's first __syncthreads drains lgkm + barriers.
  {
    const float4* wn4 = (const float4*)wnorm + (size_t)nb128 * 128 + (kg0 >> 2);
    #pragma unroll
    for (int j = 0; j < QPR / 2; ++j) {          // (128*QPR)/256 iterations
      int f    = j * 256 + tid;
      int row  = f / QPR;                        // QPR is pow2
      int quad = f % QPR;
      float4 v = wn4[(size_t)row * 128 + quad];
      NRM[(quad * 4 + 0) * 128 + row] = v.x;
      NRM[(quad * 4 + 1) * 128 + row] = v.y;
      NRM[(quad * 4 + 2) * 128 + row] = v.z;
      NRM[(quad * 4 + 3) * 128 + row] = v.w;
    }
  }

  // STAGE = exactly 5 x 16B global_load_lds per thread, all LDS-linear.
  // pk rows are 96 B = 6x16 B, so 16B DMAs never straddle a row (proven r6/r7).
#define STAGE(BUF, KT)                                                        \
  do {                                                                        \
    _Pragma("unroll")                                                         \
    for (int i = 0; i < 3; ++i) {                                             \
      int t   = tid * 16 + i * 4096;                                          \
      int row = (int)(((unsigned)t * 43691u) >> 22);  /* t/96 */              \
      int off = t - row * 96;                                                 \
      gl_lds16(wqp + (size_t)row * 12288 + (KT) * 96 + off,                   \
               &LDS[BUF][i * 4096 + w * 1024]);                               \
    }                                                                         \
    _Pragma("unroll")                                                         \
    for (int i = 0; i < 2; ++i) {                                             \
      int row = (tid >> 3) + i * 32;                                          \
      int c   = tid & 7;                                                      \
      int cs  = c ^ (row & 7);                                                \
      gl_lds16(xbp + (size_t)row * (IN_F * 2) + (KT) * 128 + cs * 16,         \
               &LDS[BUF][PK_BYTES + i * 4096 + w * 1024]);                    \
    }                                                                         \
  } while (0)

#define COMPUTE(BUF, KT)                                                      \
  do {                                                                        \
    const char* pk = &LDS[BUF][0];                                            \
    const char* pa = &LDS[BUF][PK_BYTES];                                     \
    _Pragma("unroll")                                                         \
    for (int ks = 0; ks < 2; ++ks) {                                          \
      bf16x8 af[4];                                                           \
      _Pragma("unroll")                                                       \
      for (int m = 0; m < 4; ++m) {                                           \
        int row = m * 16 + l15;                                               \
        int cch = ks * 4 + h;                                                 \
        af[m] = *(const bf16x8*)(pa + row * 128 + ((cch ^ (row & 7)) * 16));  \
      }                                                                       \
      bf16x8 bfr[2];                                                          \
      _Pragma("unroll")                                                       \
      for (int n = 0; n < 2; ++n) {                                           \
        int r_loc = w * 32 + n * 16 + l15;                                    \
        int g = ks * 2 + (h >> 1);                                            \
        const uint* p = (const uint*)(pk + r_loc * 96 + g * 24 + (h & 1) * 12); \
        bfr[n] = dqfrag(p[0], p[1], p[2], NRM[((KT) * 4 + g) * 128 + r_loc]); \
      }                                                                       \
      _Pragma("unroll")                                                       \
      for (int m = 0; m < 4; ++m)                                             \
        _Pragma("unroll")                                                     \
        for (int n = 0; n < 2; ++n)                                           \
          acc[n][m] = __builtin_amdgcn_mfma_f32_16x16x32_bf16(af[m], bfr[n],  \
                                                              acc[n][m], 0, 0, 0); \
    }                                                                         \
  } while (0)

  STAGE(0, 0);

  #pragma unroll
  for (int kt = 0; kt < NTILE; ++kt) {
    __syncthreads();                      // drains DMA (vmcnt) + lgkm, syncs block
    if (kt + 1 < NTILE) STAGE((kt + 1) & 1, kt + 1);  // in flight across compute
    COMPUTE(kt & 1, kt);
  }

#undef STAGE
#undef COMPUTE

  // C/D layout: col = lane&15, row = (lane>>4)*4 + r (verified m89)
  float* pout = partial + (size_t)s * BATCH * OUT_F;
  #pragma unroll
  for (int n = 0; n < 2; ++n) {
    int col = nb128 + w * 32 + n * 16 + l15;
    #pragma unroll
    for (int m = 0; m < 4; ++m) {
      int rowb = m * 16 + h * 4;
      #pragma unroll
      for (int r = 0; r < 4; ++r)
        pout[(size_t)(rowb + r) * OUT_F + col] = acc[n][m][r];
    }
  }
}

template <int KS>
__global__ void __launch_bounds__(256) reduce_kernel(const float* __restrict__ partial,
                                                     const float* __restrict__ bias,
                                                     float* __restrict__ out) {
  int i = blockIdx.x * 256 + threadIdx.x;
  float4 a = ((const float4*)partial)[i];
  #pragma unroll
  for (int s2 = 1; s2 < KS; ++s2) {
    float4 b = ((const float4*)partial)[i + s2 * (BATCH * OUT_F / 4)];
    a.x += b.x; a.y += b.y; a.z += b.z; a.w += b.w;
  }
  float4 bv = ((const float4*)bias)[i & (OUT_F / 4 - 1)];
  a.x += bv.x; a.y += bv.y; a.z += bv.z; a.w += bv.w;
  ((float4*)out)[i] = a;
}

extern "C" void kernel_launch(void* const* d_in, const int* in_sizes, int n_in,
                              void* d_out, int out_size, void* d_ws, size_t ws_size,
                              hipStream_t stream) {
  const float* x     = (const float*)d_in[0];
  const int*   wq    = (const int*)d_in[1];
  const float* wnorm = (const float*)d_in[2];
  const float* bias  = (const float*)d_in[3];
  float* out = (float*)d_out;

  const size_t xb_bytes = (size_t)BATCH * IN_F * 2;  // 1 MB
  ushort* xb      = (ushort*)d_ws;
  float*  partial = (float*)((char*)d_ws + xb_bytes);

  hipLaunchKernelGGL(xcvt_kernel, dim3(BATCH * IN_F / 4 / 256), dim3(256), 0, stream, x, xb);

  const size_t slice_bytes = (size_t)BATCH * OUT_F * 4;  // 2 MB per k-slice
  if (ws_size >= xb_bytes + 16 * slice_bytes) {
    hipLaunchKernelGGL((gemm3b_kernel<16>), dim3(OUT_F / 128, 16), dim3(256), 0, stream,
                       xb, wq, wnorm, partial);
    hipLaunchKernelGGL((reduce_kernel<16>), dim3(BATCH * OUT_F / 4 / 256), dim3(256), 0, stream,
                       partial, bias, out);
  } else if (ws_size >= xb_bytes + 8 * slice_bytes) {
    hipLaunchKernelGGL((gemm3b_kernel<8>), dim3(OUT_F / 128, 8), dim3(256), 0, stream,
                       xb, wq, wnorm, partial);
    hipLaunchKernelGGL((reduce_kernel<8>), dim3(BATCH * OUT_F / 4 / 256), dim3(256), 0, stream,
                       partial, bias, out);
  } else {
    hipLaunchKernelGGL((gemm3b_kernel<4>), dim3(OUT_F / 128, 4), dim3(256), 0, stream,
                       xb, wq, wnorm, partial);
    hipLaunchKernelGGL((reduce_kernel<4>), dim3(BATCH * OUT_F / 4 / 256), dim3(256), 0, stream,
                       partial, bias, out);
  }
}